// Round 1
// baseline (707.018 us; speedup 1.0000x reference)
//
#include <hip/hip_runtime.h>

#define NN 100000
#define NE 800000
// D = 160, 2D = 320, F = 128

typedef _Float16 half8 __attribute__((ext_vector_type(8)));
typedef _Float16 half4 __attribute__((ext_vector_type(4)));
typedef float floatx4 __attribute__((ext_vector_type(4)));

// ---------------------------------------------------------------- zero
__global__ __launch_bounds__(256) void k_zero(float4* __restrict__ p, int n4) {
  int i = blockIdx.x * 256 + threadIdx.x;
  if (i < n4) p[i] = make_float4(0.f, 0.f, 0.f, 0.f);
}

// ---------------------------------------------------------------- weight casts
__global__ __launch_bounds__(256) void k_cast(const float* __restrict__ s,
                                              _Float16* __restrict__ d, int n) {
  int i = blockIdx.x * 256 + threadIdx.x;
  if (i < n) d[i] = (_Float16)s[i];
}
// Wp[l][j2][k] (j2<160: wm[l][j2][k], else wm[l][j2-160][160+k]); total 2*320*160
__global__ __launch_bounds__(256) void k_prep_wm(const float* __restrict__ wm,
                                                 _Float16* __restrict__ Wp) {
  int i = blockIdx.x * 256 + threadIdx.x;
  if (i >= 102400) return;
  int l = i / 51200, rem = i - l * 51200;
  int j2 = rem / 160, k = rem - j2 * 160;
  float v = (j2 < 160) ? wm[l * 51200 + j2 * 320 + k]
                       : wm[l * 51200 + (j2 - 160) * 320 + 160 + k];
  Wp[i] = (_Float16)v;
}

// ---------------------------------------------------------------- CSR build
__global__ __launch_bounds__(256) void k_count_i(const int* __restrict__ ei,
                                                 int* __restrict__ cnti) {
  int e = blockIdx.x * 256 + threadIdx.x;  // grid exact: 3125*256 = 800000
  atomicAdd(&cnti[ei[NE + e]], 1);
}

__global__ __launch_bounds__(256) void k_scan1(const int* __restrict__ cnti,
                                               int* __restrict__ off,
                                               int* __restrict__ bsum) {
  __shared__ int sh[256];
  const int t = threadIdx.x;
  const int i = blockIdx.x * 256 + t;  // grid 391 covers 100096
  int v = (i < NN) ? cnti[i] : 0;
  sh[t] = v;
  __syncthreads();
  for (int d = 1; d < 256; d <<= 1) {
    int add = (t >= d) ? sh[t - d] : 0;
    __syncthreads();
    sh[t] += add;
    __syncthreads();
  }
  if (i < NN) off[i] = sh[t] - v;
  if (t == 255) bsum[blockIdx.x] = sh[255];
}

__global__ __launch_bounds__(512) void k_scan2(const int* __restrict__ bsum,
                                               int* __restrict__ bsum2) {
  __shared__ int sh[512];
  const int t = threadIdx.x;
  int v = (t < 391) ? bsum[t] : 0;
  sh[t] = v;
  __syncthreads();
  for (int d = 1; d < 512; d <<= 1) {
    int add = (t >= d) ? sh[t - d] : 0;
    __syncthreads();
    sh[t] += add;
    __syncthreads();
  }
  if (t < 391) bsum2[t] = sh[t] - v;
}

__global__ __launch_bounds__(256) void k_scan3(int* __restrict__ off,
                                               const int* __restrict__ bsum2,
                                               int* __restrict__ cursor) {
  const int i = blockIdx.x * 256 + threadIdx.x;
  if (i < NN) {
    int o = off[i] + bsum2[blockIdx.x];
    off[i] = o;
    cursor[i] = o;
  }
  if (i == 0) off[NN] = NE;
}

__global__ __launch_bounds__(256) void k_scatter(const int* __restrict__ ei,
                                                 const float* __restrict__ ew,
                                                 int* __restrict__ cursor,
                                                 int2* __restrict__ selist) {
  int e = blockIdx.x * 256 + threadIdx.x;  // grid exact 3125
  int dst = ei[NE + e];
  int pos = atomicAdd(&cursor[dst], 1);
  selist[pos] = make_int2(ei[e], __float_as_int(ew[e]));
}

// ---------------------------------------------------------------- B-panel staging
// Stage nj rows x kw halfs (K-contiguous) of W (row stride SR) into Bsh (row
// stride 168 halfs = 21x16B units, 21 odd -> uniform 8-phase bank pattern for
// b128 fragment reads at any 32-half k-tile offset).
__device__ __forceinline__ void stage_B(_Float16* Bsh, const _Float16* W, int SR,
                                        int k0, int nj, int kw, int t) {
  const int pc = kw >> 3;          // 16-B pieces per row
  const int chunks = nj * pc;
  for (int c = t; c < chunks; c += 256) {
    int j = c / pc, piece = c - j * pc;
    *(half8*)&Bsh[j * 168 + piece * 8] = *(const half8*)&W[(size_t)j * SR + k0 + piece * 8];
  }
}

// ---------------------------------------------------------------- fused encoder + proj
__global__ __launch_bounds__(256) void k_encode_proj(
    const float* __restrict__ x, const float* __restrict__ tsp,
    const _Float16* __restrict__ We,
    const float* __restrict__ b_enc, const float* __restrict__ g_enc,
    const float* __restrict__ be_enc,
    const float* __restrict__ w_time, const float* __restrict__ b_time,
    const float* __restrict__ g_time, const float* __restrict__ be_time,
    const _Float16* __restrict__ Wp, const float* __restrict__ bm,
    _Float16* __restrict__ h16, _Float16* __restrict__ P) {
  __shared__ _Float16 tile[64 * 168];
  __shared__ _Float16 Bsh[160 * 168];
  const int t = threadIdx.x;
  const int lane = t & 63, w = t >> 6;
  const int mrow = lane & 15, quad = lane >> 4;
  const int n0 = blockIdx.x * 64;  // grid 1563
  int arow = n0 + w * 16 + mrow; if (arow > NN - 1) arow = NN - 1;
  // stage full We (128 rows x K=128) once, ASAP
  stage_B(Bsh, We, 128, 0, 128, 128, t);
  const float* xrow = x + (size_t)arow * 128;
  // hoist all A fragments (f32 -> f16) — overlaps staging latency
  half8 areg[4];
#pragma unroll
  for (int kt = 0; kt < 4; ++kt) {
    const int k0 = kt * 32 + quad * 8;
    float4 f0 = *(const float4*)&xrow[k0];
    float4 f1 = *(const float4*)&xrow[k0 + 4];
    half8 a = {(_Float16)f0.x, (_Float16)f0.y, (_Float16)f0.z, (_Float16)f0.w,
               (_Float16)f1.x, (_Float16)f1.y, (_Float16)f1.z, (_Float16)f1.w};
    areg[kt] = a;
  }
  // time-LN closed-form constants — also overlaps staging latency
  float mw = 0.f, mb = 0.f;
  for (int d = 0; d < 32; ++d) { mw += w_time[d]; mb += b_time[d]; }
  mw *= (1.f / 32.f); mb *= (1.f / 32.f);
  float A = 0.f, B = 0.f, C = 0.f;
  for (int d = 0; d < 32; ++d) {
    float a = w_time[d] - mw, c = b_time[d] - mb;
    A = fmaf(a, a, A); B = fmaf(a, c, B); C = fmaf(c, c, C);
  }
  A *= (1.f / 32.f); B *= (1.f / 32.f); C *= (1.f / 32.f);
  floatx4 acc[8];
#pragma unroll
  for (int i = 0; i < 8; ++i) acc[i] = (floatx4)0.f;
  __syncthreads();
#pragma unroll
  for (int h2 = 0; h2 < 4; ++h2) {
    half8 a = areg[h2];
#pragma unroll
    for (int i = 0; i < 8; ++i) {
      half8 b = *(const half8*)&Bsh[(i * 16 + mrow) * 168 + h2 * 32 + quad * 8];
      acc[i] = __builtin_amdgcn_mfma_f32_16x16x32_f16(a, b, acc[i], 0, 0, 0);
    }
  }
  // epilogue: LN(128) + relu -> tile + h16
#pragma unroll
  for (int r = 0; r < 4; ++r) {
    const int row = quad * 4 + r;
    const int node = n0 + w * 16 + row;
    float v[8], s = 0.f, ss = 0.f;
#pragma unroll
    for (int i = 0; i < 8; ++i) {
      v[i] = acc[i][r] + b_enc[i * 16 + mrow];
      s += v[i]; ss = fmaf(v[i], v[i], ss);
    }
#pragma unroll
    for (int off = 1; off < 16; off <<= 1) { s += __shfl_xor(s, off); ss += __shfl_xor(ss, off); }
    const float m = s * (1.f / 128.f);
    const float rs = rsqrtf(ss * (1.f / 128.f) - m * m + 1e-5f);
#pragma unroll
    for (int i = 0; i < 8; ++i) {
      int j = i * 16 + mrow;
      float y = fmaxf(fmaf((v[i] - m) * rs, g_enc[j], be_enc[j]), 0.f);
      tile[(w * 16 + row) * 168 + j] = (_Float16)y;
      if (node < NN) h16[(size_t)node * 160 + j] = (_Float16)y;
    }
  }
  // time dims 128..159 (closed-form LN)
#pragma unroll
  for (int r2 = 0; r2 < 8; ++r2) {
    int q = t + r2 * 256;  // 2048 = 64 nodes x 32 dims
    int nn = q >> 5, d = q & 31;
    int node = n0 + nn;
    int nodec = (node > NN - 1) ? NN - 1 : node;
    float tsv = tsp[nodec];
    float mt = fmaf(mw, tsv, mb);
    float rst = rsqrtf(fmaf(fmaf(A, tsv, 2.f * B), tsv, C) + 1e-5f);
    float vv = fmaf(w_time[d], tsv, b_time[d]);
    float y = fmaxf(fmaf((vv - mt) * rst, g_time[d], be_time[d]), 0.f);
    tile[nn * 168 + 128 + d] = (_Float16)y;
    if (node < NN) h16[(size_t)node * 160 + 128 + d] = (_Float16)y;
  }
  // ---- phase 2: P = tile @ Wp^T, 2 col-halves of 160, one full-K stage each
#pragma unroll 1
  for (int half_ = 0; half_ < 2; ++half_) {
    __syncthreads();
    stage_B(Bsh, Wp + (size_t)half_ * 160 * 160, 160, 0, 160, 160, t);
    __syncthreads();
    floatx4 acc2[10];
#pragma unroll
    for (int i = 0; i < 10; ++i) acc2[i] = (floatx4)0.f;
#pragma unroll
    for (int h2 = 0; h2 < 5; ++h2) {
      half8 a = *(const half8*)&tile[(w * 16 + mrow) * 168 + h2 * 32 + quad * 8];
#pragma unroll
      for (int i = 0; i < 10; ++i) {
        half8 b = *(const half8*)&Bsh[(i * 16 + mrow) * 168 + h2 * 32 + quad * 8];
        acc2[i] = __builtin_amdgcn_mfma_f32_16x16x32_f16(a, b, acc2[i], 0, 0, 0);
      }
    }
#pragma unroll
    for (int r = 0; r < 4; ++r) {
      const int row = quad * 4 + r;
      const int node = n0 + w * 16 + row;
      if (node < NN) {
        _Float16* prow = &P[(size_t)node * 320 + half_ * 160];
#pragma unroll
        for (int i = 0; i < 10; ++i) {
          int jj = i * 16 + mrow;
          float v2 = acc2[i][r] + (half_ ? bm[jj] : 0.f);
          prow[jj] = (_Float16)v2;
        }
      }
    }
  }
}

// ---------------------------------------------------------------- edge aggregate (CSR, 2-way unroll)
__global__ __launch_bounds__(256) void k_edge3(
    const _Float16* __restrict__ P, const int* __restrict__ off,
    const int2* __restrict__ selist,
    const float* __restrict__ gm, const float* __restrict__ bem,
    _Float16* __restrict__ msum16) {
  const int t = threadIdx.x;
  const int jg = t & 31, g = t >> 5;
  const int n = blockIdx.x * 8 + g;  // grid exact: 12500*8 = 100000
  float gmv[5], bev[5], pdv[5];
#pragma unroll
  for (int i = 0; i < 4; ++i) { gmv[i] = gm[4 * jg + i]; bev[i] = bem[4 * jg + i]; }
  gmv[4] = gm[128 + jg]; bev[4] = bem[128 + jg];
  const _Float16* pd = P + (size_t)n * 320 + 160;
  half4 pdh = *(const half4*)&pd[4 * jg];
  pdv[0] = (float)pdh.x; pdv[1] = (float)pdh.y; pdv[2] = (float)pdh.z; pdv[3] = (float)pdh.w;
  pdv[4] = (float)pd[128 + jg];
  float acc[5] = {0.f, 0.f, 0.f, 0.f, 0.f};
  const int e0 = off[n], e1 = off[n + 1];
  int k = e0;
  for (; k + 1 < e1; k += 2) {
    int2 seA = selist[k], seB = selist[k + 1];
    const _Float16* psA = P + (size_t)seA.x * 320;
    const _Float16* psB = P + (size_t)seB.x * 320;
    const float weA = __int_as_float(seA.y), weB = __int_as_float(seB.y);
    half4 a4 = *(const half4*)&psA[4 * jg];
    half4 b4 = *(const half4*)&psB[4 * jg];
    float a5 = (float)psA[128 + jg], b5 = (float)psB[128 + jg];
    float vA[5], vB[5];
    vA[0] = (float)a4.x + pdv[0]; vA[1] = (float)a4.y + pdv[1];
    vA[2] = (float)a4.z + pdv[2]; vA[3] = (float)a4.w + pdv[3]; vA[4] = a5 + pdv[4];
    vB[0] = (float)b4.x + pdv[0]; vB[1] = (float)b4.y + pdv[1];
    vB[2] = (float)b4.z + pdv[2]; vB[3] = (float)b4.w + pdv[3]; vB[4] = b5 + pdv[4];
    float sA = 0.f, ssA = 0.f, sB = 0.f, ssB = 0.f;
#pragma unroll
    for (int i = 0; i < 5; ++i) {
      sA += vA[i]; ssA = fmaf(vA[i], vA[i], ssA);
      sB += vB[i]; ssB = fmaf(vB[i], vB[i], ssB);
    }
#pragma unroll
    for (int o = 1; o < 32; o <<= 1) {
      sA += __shfl_xor(sA, o); ssA += __shfl_xor(ssA, o);
      sB += __shfl_xor(sB, o); ssB += __shfl_xor(ssB, o);
    }
    const float mA = sA * (1.f / 160.f), mB = sB * (1.f / 160.f);
    const float rsA = rsqrtf(ssA * (1.f / 160.f) - mA * mA + 1e-5f);
    const float rsB = rsqrtf(ssB * (1.f / 160.f) - mB * mB + 1e-5f);
#pragma unroll
    for (int i = 0; i < 5; ++i) {
      acc[i] = fmaf(fmaxf(fmaf((vA[i] - mA) * rsA, gmv[i], bev[i]), 0.f), weA, acc[i]);
      acc[i] = fmaf(fmaxf(fmaf((vB[i] - mB) * rsB, gmv[i], bev[i]), 0.f), weB, acc[i]);
    }
  }
  if (k < e1) {
    int2 se = selist[k];
    const _Float16* ps = P + (size_t)se.x * 320;
    const float we = __int_as_float(se.y);
    half4 s4 = *(const half4*)&ps[4 * jg];
    float v[5], s = 0.f, ss = 0.f;
    v[0] = (float)s4.x + pdv[0]; v[1] = (float)s4.y + pdv[1];
    v[2] = (float)s4.z + pdv[2]; v[3] = (float)s4.w + pdv[3];
    v[4] = (float)ps[128 + jg] + pdv[4];
#pragma unroll
    for (int i = 0; i < 5; ++i) { s += v[i]; ss = fmaf(v[i], v[i], ss); }
#pragma unroll
    for (int o = 1; o < 32; o <<= 1) { s += __shfl_xor(s, o); ss += __shfl_xor(ss, o); }
    const float m = s * (1.f / 160.f);
    const float rs = rsqrtf(ss * (1.f / 160.f) - m * m + 1e-5f);
#pragma unroll
    for (int i = 0; i < 5; ++i)
      acc[i] = fmaf(fmaxf(fmaf((v[i] - m) * rs, gmv[i], bev[i]), 0.f), we, acc[i]);
  }
  const float c = (float)(e1 - e0);
  const float ic = (c > 0.f) ? 1.f / (c + 1e-8f) : 0.f;
  _Float16* orow = msum16 + (size_t)n * 160;
  half4 o4 = {(_Float16)(acc[0] * ic), (_Float16)(acc[1] * ic),
              (_Float16)(acc[2] * ic), (_Float16)(acc[3] * ic)};
  *(half4*)&orow[4 * jg] = o4;
  orow[128 + jg] = (_Float16)(acc[4] * ic);
}

// ---------------------------------------------------------------- fused update + proj (next layer)
__global__ __launch_bounds__(256) void k_update_proj(
    _Float16* __restrict__ h16, const _Float16* __restrict__ msum16,
    const _Float16* __restrict__ Wu, const float* __restrict__ bu,
    const float* __restrict__ gu, const float* __restrict__ beu,
    const float* __restrict__ wg, const float* __restrict__ bg,
    const _Float16* __restrict__ Wp, const float* __restrict__ bm,
    _Float16* __restrict__ P) {
  __shared__ _Float16 tile[64 * 168];
  __shared__ _Float16 Bsh[160 * 168];
  const int t = threadIdx.x;
  const int lane = t & 63, w = t >> 6;
  const int mrow = lane & 15, quad = lane >> 4;
  const int n0 = blockIdx.x * 64;  // grid 1563
  int arow = n0 + w * 16 + mrow; if (arow > NN - 1) arow = NN - 1;
  // stage K-panel 0 of Wu ASAP (overlaps areg loads + gate compute)
  stage_B(Bsh, Wu, 320, 0, 160, 160, t);
  const _Float16* hrowp = h16 + (size_t)arow * 160;
  const _Float16* mrowp = msum16 + (size_t)arow * 160;
  // hoist A fragments
  half8 areg[10];
#pragma unroll
  for (int kt = 0; kt < 5; ++kt) areg[kt] = *(const half8*)&hrowp[kt * 32 + quad * 8];
#pragma unroll
  for (int kt = 5; kt < 10; ++kt) areg[kt] = *(const half8*)&mrowp[kt * 32 + quad * 8 - 160];
  // gate dot from hoisted h-fragments
  float gp = 0.f;
#pragma unroll
  for (int kt = 0; kt < 5; ++kt) {
    const int k0 = kt * 32 + quad * 8;
    float4 g0 = *(const float4*)&wg[k0];
    float4 g1 = *(const float4*)&wg[k0 + 4];
    gp = fmaf((float)areg[kt][0], g0.x, gp); gp = fmaf((float)areg[kt][1], g0.y, gp);
    gp = fmaf((float)areg[kt][2], g0.z, gp); gp = fmaf((float)areg[kt][3], g0.w, gp);
    gp = fmaf((float)areg[kt][4], g1.x, gp); gp = fmaf((float)areg[kt][5], g1.y, gp);
    gp = fmaf((float)areg[kt][6], g1.z, gp); gp = fmaf((float)areg[kt][7], g1.w, gp);
  }
  gp += __shfl_xor(gp, 16); gp += __shfl_xor(gp, 32);
  const float twv = 1.f / (1.f + expf(-(gp + bg[0])));
  floatx4 acc[10];
#pragma unroll
  for (int i = 0; i < 10; ++i) acc[i] = (floatx4)0.f;
  // K-panel 0: k = 0..159
  __syncthreads();
#pragma unroll
  for (int h2 = 0; h2 < 5; ++h2) {
    half8 a = areg[h2];
#pragma unroll
    for (int i = 0; i < 10; ++i) {
      half8 b = *(const half8*)&Bsh[(i * 16 + mrow) * 168 + h2 * 32 + quad * 8];
      acc[i] = __builtin_amdgcn_mfma_f32_16x16x32_f16(a, b, acc[i], 0, 0, 0);
    }
  }
  // K-panel 1: k = 160..319
  __syncthreads();
  stage_B(Bsh, Wu, 320, 160, 160, 160, t);
  __syncthreads();
#pragma unroll
  for (int h2 = 0; h2 < 5; ++h2) {
    half8 a = areg[5 + h2];
#pragma unroll
    for (int i = 0; i < 10; ++i) {
      half8 b = *(const half8*)&Bsh[(i * 16 + mrow) * 168 + h2 * 32 + quad * 8];
      acc[i] = __builtin_amdgcn_mfma_f32_16x16x32_f16(a, b, acc[i], 0, 0, 0);
    }
  }
  // epilogue: LN + relu + gate blend -> tile + h16
#pragma unroll
  for (int r = 0; r < 4; ++r) {
    const int row = quad * 4 + r;
    const int node = n0 + w * 16 + row;
    const int nodec = (node > NN - 1) ? NN - 1 : node;
    float v[10], s = 0.f, ss = 0.f;
#pragma unroll
    for (int i = 0; i < 10; ++i) {
      v[i] = acc[i][r] + bu[i * 16 + mrow];
      s += v[i]; ss = fmaf(v[i], v[i], ss);
    }
#pragma unroll
    for (int off = 1; off < 16; off <<= 1) { s += __shfl_xor(s, off); ss += __shfl_xor(ss, off); }
    const float m = s * (1.f / 160.f);
    const float rs = rsqrtf(ss * (1.f / 160.f) - m * m + 1e-5f);
    const float g = __shfl(twv, row);
    const _Float16* hr = h16 + (size_t)nodec * 160;
#pragma unroll
    for (int i = 0; i < 10; ++i) {
      int j = i * 16 + mrow;
      float hnew = fmaxf(fmaf((v[i] - m) * rs, gu[j], beu[j]), 0.f);
      float hold = (float)hr[j];
      float hupd = fmaf(g, hnew - hold, hold);
      tile[(w * 16 + row) * 168 + j] = (_Float16)hupd;
      if (node < NN) h16[(size_t)node * 160 + j] = (_Float16)hupd;
    }
  }
  // ---- phase 2: P = tile @ Wp^T, 2 col-halves of 160, one full-K stage each
#pragma unroll 1
  for (int half_ = 0; half_ < 2; ++half_) {
    __syncthreads();
    stage_B(Bsh, Wp + (size_t)half_ * 160 * 160, 160, 0, 160, 160, t);
    __syncthreads();
    floatx4 acc2[10];
#pragma unroll
    for (int i = 0; i < 10; ++i) acc2[i] = (floatx4)0.f;
#pragma unroll
    for (int h2 = 0; h2 < 5; ++h2) {
      half8 a = *(const half8*)&tile[(w * 16 + mrow) * 168 + h2 * 32 + quad * 8];
#pragma unroll
      for (int i = 0; i < 10; ++i) {
        half8 b = *(const half8*)&Bsh[(i * 16 + mrow) * 168 + h2 * 32 + quad * 8];
        acc2[i] = __builtin_amdgcn_mfma_f32_16x16x32_f16(a, b, acc2[i], 0, 0, 0);
      }
    }
#pragma unroll
    for (int r = 0; r < 4; ++r) {
      const int row = quad * 4 + r;
      const int node = n0 + w * 16 + row;
      if (node < NN) {
        _Float16* prow = &P[(size_t)node * 320 + half_ * 160];
#pragma unroll
        for (int i = 0; i < 10; ++i) {
          int jj = i * 16 + mrow;
          float v2 = acc2[i][r] + (half_ ? bm[jj] : 0.f);
          prow[jj] = (_Float16)v2;
        }
      }
    }
  }
}

// ---------------------------------------------------------------- fused update + output proj + L2 norm
__global__ __launch_bounds__(256) void k_update_out(
    const _Float16* __restrict__ h16, const _Float16* __restrict__ msum16,
    const _Float16* __restrict__ Wu, const float* __restrict__ bu,
    const float* __restrict__ gu, const float* __restrict__ beu,
    const float* __restrict__ wg, const float* __restrict__ bg,
    const _Float16* __restrict__ Wo, const float* __restrict__ b_out,
    float* __restrict__ out) {
  __shared__ _Float16 tile[64 * 168];
  __shared__ _Float16 Bsh[160 * 168];
  const int t = threadIdx.x;
  const int lane = t & 63, w = t >> 6;
  const int mrow = lane & 15, quad = lane >> 4;
  const int n0 = blockIdx.x * 64;  // grid 1563
  int arow = n0 + w * 16 + mrow; if (arow > NN - 1) arow = NN - 1;
  // stage K-panel 0 of Wu ASAP
  stage_B(Bsh, Wu, 320, 0, 160, 160, t);
  const _Float16* hrowp = h16 + (size_t)arow * 160;
  const _Float16* mrowp = msum16 + (size_t)arow * 160;
  half8 areg[10];
#pragma unroll
  for (int kt = 0; kt < 5; ++kt) areg[kt] = *(const half8*)&hrowp[kt * 32 + quad * 8];
#pragma unroll
  for (int kt = 5; kt < 10; ++kt) areg[kt] = *(const half8*)&mrowp[kt * 32 + quad * 8 - 160];
  float gp = 0.f;
#pragma unroll
  for (int kt = 0; kt < 5; ++kt) {
    const int k0 = kt * 32 + quad * 8;
    float4 g0 = *(const float4*)&wg[k0];
    float4 g1 = *(const float4*)&wg[k0 + 4];
    gp = fmaf((float)areg[kt][0], g0.x, gp); gp = fmaf((float)areg[kt][1], g0.y, gp);
    gp = fmaf((float)areg[kt][2], g0.z, gp); gp = fmaf((float)areg[kt][3], g0.w, gp);
    gp = fmaf((float)areg[kt][4], g1.x, gp); gp = fmaf((float)areg[kt][5], g1.y, gp);
    gp = fmaf((float)areg[kt][6], g1.z, gp); gp = fmaf((float)areg[kt][7], g1.w, gp);
  }
  gp += __shfl_xor(gp, 16); gp += __shfl_xor(gp, 32);
  const float twv = 1.f / (1.f + expf(-(gp + bg[0])));
  floatx4 acc[10];
#pragma unroll
  for (int i = 0; i < 10; ++i) acc[i] = (floatx4)0.f;
  // K-panel 0
  __syncthreads();
#pragma unroll
  for (int h2 = 0; h2 < 5; ++h2) {
    half8 a = areg[h2];
#pragma unroll
    for (int i = 0; i < 10; ++i) {
      half8 b = *(const half8*)&Bsh[(i * 16 + mrow) * 168 + h2 * 32 + quad * 8];
      acc[i] = __builtin_amdgcn_mfma_f32_16x16x32_f16(a, b, acc[i], 0, 0, 0);
    }
  }
  // K-panel 1
  __syncthreads();
  stage_B(Bsh, Wu, 320, 160, 160, 160, t);
  __syncthreads();
#pragma unroll
  for (int h2 = 0; h2 < 5; ++h2) {
    half8 a = areg[5 + h2];
#pragma unroll
    for (int i = 0; i < 10; ++i) {
      half8 b = *(const half8*)&Bsh[(i * 16 + mrow) * 168 + h2 * 32 + quad * 8];
      acc[i] = __builtin_amdgcn_mfma_f32_16x16x32_f16(a, b, acc[i], 0, 0, 0);
    }
  }
#pragma unroll
  for (int r = 0; r < 4; ++r) {
    const int row = quad * 4 + r;
    const int node = n0 + w * 16 + row;
    const int nodec = (node > NN - 1) ? NN - 1 : node;
    float v[10], s = 0.f, ss = 0.f;
#pragma unroll
    for (int i = 0; i < 10; ++i) {
      v[i] = acc[i][r] + bu[i * 16 + mrow];
      s += v[i]; ss = fmaf(v[i], v[i], ss);
    }
#pragma unroll
    for (int off = 1; off < 16; off <<= 1) { s += __shfl_xor(s, off); ss += __shfl_xor(ss, off); }
    const float m = s * (1.f / 160.f);
    const float rs = rsqrtf(ss * (1.f / 160.f) - m * m + 1e-5f);
    const float g = __shfl(twv, row);
    const _Float16* hr = h16 + (size_t)nodec * 160;
#pragma unroll
    for (int i = 0; i < 10; ++i) {
      int j = i * 16 + mrow;
      float hnew = fmaxf(fmaf((v[i] - m) * rs, gu[j], beu[j]), 0.f);
      float hold = (float)hr[j];
      tile[(w * 16 + row) * 168 + j] = (_Float16)fmaf(g, hnew - hold, hold);  // final h: LDS only
    }
  }
  // ---- phase 2: out = L2norm(tile @ Wo^T + b_out); 128 cols, K=160, one stage
  __syncthreads();
  stage_B(Bsh, Wo, 160, 0, 128, 160, t);
  __syncthreads();
  floatx4 acc2[8];
#pragma unroll
  for (int i = 0; i < 8; ++i) acc2[i] = (floatx4)0.f;
#pragma unroll
  for (int h2 = 0; h2 < 5; ++h2) {
    half8 a = *(const half8*)&tile[(w * 16 + mrow) * 168 + h2 * 32 + quad * 8];
#pragma unroll
    for (int i = 0; i < 8; ++i) {
      half8 b = *(const half8*)&Bsh[(i * 16 + mrow) * 168 + h2 * 32 + quad * 8];
      acc2[i] = __builtin_amdgcn_mfma_f32_16x16x32_f16(a, b, acc2[i], 0, 0, 0);
    }
  }
#pragma unroll
  for (int r = 0; r < 4; ++r) {
    const int row = quad * 4 + r;
    const int node = n0 + w * 16 + row;
    float v[8], ss = 0.f;
#pragma unroll
    for (int i = 0; i < 8; ++i) {
      v[i] = acc2[i][r] + b_out[i * 16 + mrow];
      ss = fmaf(v[i], v[i], ss);
    }
#pragma unroll
    for (int off = 1; off < 16; off <<= 1) ss += __shfl_xor(ss, off);
    const float inv = 1.f / fmaxf(sqrtf(ss), 1e-12f);
    if (node < NN) {
#pragma unroll
      for (int i = 0; i < 8; ++i)
        out[(size_t)node * 128 + i * 16 + mrow] = v[i] * inv;
    }
  }
}

// ---------------------------------------------------------------- launch
extern "C" void kernel_launch(void* const* d_in, const int* in_sizes, int n_in,
                              void* d_out, int out_size, void* d_ws, size_t ws_size,
                              hipStream_t stream) {
  (void)in_sizes; (void)n_in; (void)out_size; (void)ws_size;
  const float* x       = (const float*)d_in[0];
  const int*   ei      = (const int*)  d_in[1];
  const float* ew      = (const float*)d_in[2];
  const float* tsp     = (const float*)d_in[3];
  const float* w_enc   = (const float*)d_in[4];
  const float* b_enc   = (const float*)d_in[5];
  const float* g_enc   = (const float*)d_in[6];
  const float* be_enc  = (const float*)d_in[7];
  const float* w_time  = (const float*)d_in[8];
  const float* b_time  = (const float*)d_in[9];
  const float* g_time  = (const float*)d_in[10];
  const float* be_time = (const float*)d_in[11];
  const float* wm      = (const float*)d_in[12];
  const float* bm      = (const float*)d_in[13];
  const float* gm      = (const float*)d_in[14];
  const float* bem     = (const float*)d_in[15];
  const float* wu      = (const float*)d_in[16];
  const float* bu      = (const float*)d_in[17];
  const float* gu      = (const float*)d_in[18];
  const float* beu     = (const float*)d_in[19];
  const float* wg      = (const float*)d_in[20];
  const float* bg      = (const float*)d_in[21];
  const float* w_out   = (const float*)d_in[22];
  const float* b_out   = (const float*)d_in[23];
  float* out = (float*)d_out;

  // ws layout (bytes): h16 f16[NN*160] @0 (32M) | msum16 f16[NN*160] @32,000,000 (32M)
  //   P f16[NN*320] @64,000,000 (64M) | Wu16 @128,000,000 (204,800) | Wo16 @128,204,800 (40,960)
  char* ws = (char*)d_ws;
  _Float16* h16     = (_Float16*)ws;
  _Float16* msum16  = (_Float16*)(ws + 32000000);
  _Float16* P       = (_Float16*)(ws + 64000000);
  _Float16* Wu16    = (_Float16*)(ws + 128000000);
  _Float16* Wo16    = (_Float16*)(ws + 128204800);
  // d_out doubles as scratch; k_update_out reads only ws-resident scratch.
  char* ob = (char*)d_out;
  _Float16* Wp16 = (_Float16*)ob;             // 204,800
  _Float16* We16 = (_Float16*)(ob + 204800);  // 32,768
  int* off    = (int*)(ob + 237568);          // 400,016
  int* cnti   = (int*)(ob + 637584);          // 400,000
  int* cursor = (int*)(ob + 1037584);         // 400,000
  int* bsum   = (int*)(ob + 1437584);         // 1,568
  int* bsum2  = (int*)(ob + 1439152);         // 1,568
  int2* selist = (int2*)(ob + 1440720);       // 6,400,000 -> 7,840,720 < 51,200,000

  // weight prep + CSR build (edges static across layers: build once)
  k_zero<<<dim3(98), dim3(256), 0, stream>>>((float4*)cnti, 25000);
  k_cast<<<dim3(400), dim3(256), 0, stream>>>(wu, Wu16, 102400);
  k_cast<<<dim3(64),  dim3(256), 0, stream>>>(w_enc, We16, 16384);
  k_cast<<<dim3(80),  dim3(256), 0, stream>>>(w_out, Wo16, 20480);
  k_prep_wm<<<dim3(400), dim3(256), 0, stream>>>(wm, Wp16);
  k_count_i<<<dim3(3125), dim3(256), 0, stream>>>(ei, cnti);
  k_scan1<<<dim3(391), dim3(256), 0, stream>>>(cnti, off, bsum);
  k_scan2<<<dim3(1), dim3(512), 0, stream>>>(bsum, bsum2);
  k_scan3<<<dim3(391), dim3(256), 0, stream>>>(off, bsum2, cursor);
  k_scatter<<<dim3(3125), dim3(256), 0, stream>>>(ei, ew, cursor, selist);

  k_encode_proj<<<dim3(1563), dim3(256), 0, stream>>>(
      x, tsp, We16, b_enc, g_enc, be_enc, w_time, b_time, g_time, be_time,
      Wp16, bm, h16, P);
  k_edge3<<<dim3(12500), dim3(256), 0, stream>>>(P, off, selist, gm, bem, msum16);
  k_update_proj<<<dim3(1563), dim3(256), 0, stream>>>(
      h16, msum16, Wu16, bu, gu, beu, wg, bg,
      Wp16 + 51200, bm + 160, P);
  k_edge3<<<dim3(12500), dim3(256), 0, stream>>>(P, off, selist, gm + 160, bem + 160, msum16);
  k_update_out<<<dim3(1563), dim3(256), 0, stream>>>(
      h16, msum16, Wu16 + 51200, bu + 160, gu + 160, beu + 160, wg + 160, bg + 1,
      Wo16, b_out, out);
}

// Round 2
// 566.546 us; speedup vs baseline: 1.2479x; 1.2479x over previous
//
#include <hip/hip_runtime.h>

#define NN 100000
#define NE 800000
// D = 160, 2D = 320, F = 128

typedef _Float16 half8 __attribute__((ext_vector_type(8)));
typedef _Float16 half4 __attribute__((ext_vector_type(4)));
typedef float floatx4 __attribute__((ext_vector_type(4)));

// ---------------------------------------------------------------- zero
__global__ __launch_bounds__(256) void k_zero(float4* __restrict__ p, int n4) {
  int i = blockIdx.x * 256 + threadIdx.x;
  if (i < n4) p[i] = make_float4(0.f, 0.f, 0.f, 0.f);
}

// ---------------------------------------------------------------- weight casts
__global__ __launch_bounds__(256) void k_cast(const float* __restrict__ s,
                                              _Float16* __restrict__ d, int n) {
  int i = blockIdx.x * 256 + threadIdx.x;
  if (i < n) d[i] = (_Float16)s[i];
}
// Wp[l][j2][k] (j2<160: wm[l][j2][k], else wm[l][j2-160][160+k]); total 2*320*160
__global__ __launch_bounds__(256) void k_prep_wm(const float* __restrict__ wm,
                                                 _Float16* __restrict__ Wp) {
  int i = blockIdx.x * 256 + threadIdx.x;
  if (i >= 102400) return;
  int l = i / 51200, rem = i - l * 51200;
  int j2 = rem / 160, k = rem - j2 * 160;
  float v = (j2 < 160) ? wm[l * 51200 + j2 * 320 + k]
                       : wm[l * 51200 + (j2 - 160) * 320 + 160 + k];
  Wp[i] = (_Float16)v;
}

// ---------------------------------------------------------------- CSR build
__global__ __launch_bounds__(256) void k_count_i(const int* __restrict__ ei,
                                                 int* __restrict__ cnti) {
  int e = blockIdx.x * 256 + threadIdx.x;  // grid exact: 3125*256 = 800000
  atomicAdd(&cnti[ei[NE + e]], 1);
}

__global__ __launch_bounds__(256) void k_scan1(const int* __restrict__ cnti,
                                               int* __restrict__ off,
                                               int* __restrict__ bsum) {
  __shared__ int sh[256];
  const int t = threadIdx.x;
  const int i = blockIdx.x * 256 + t;  // grid 391 covers 100096
  int v = (i < NN) ? cnti[i] : 0;
  sh[t] = v;
  __syncthreads();
  for (int d = 1; d < 256; d <<= 1) {
    int add = (t >= d) ? sh[t - d] : 0;
    __syncthreads();
    sh[t] += add;
    __syncthreads();
  }
  if (i < NN) off[i] = sh[t] - v;
  if (t == 255) bsum[blockIdx.x] = sh[255];
}

__global__ __launch_bounds__(512) void k_scan2(const int* __restrict__ bsum,
                                               int* __restrict__ bsum2) {
  __shared__ int sh[512];
  const int t = threadIdx.x;
  int v = (t < 391) ? bsum[t] : 0;
  sh[t] = v;
  __syncthreads();
  for (int d = 1; d < 512; d <<= 1) {
    int add = (t >= d) ? sh[t - d] : 0;
    __syncthreads();
    sh[t] += add;
    __syncthreads();
  }
  if (t < 391) bsum2[t] = sh[t] - v;
}

__global__ __launch_bounds__(256) void k_scan3(int* __restrict__ off,
                                               const int* __restrict__ bsum2,
                                               int* __restrict__ cursor) {
  const int i = blockIdx.x * 256 + threadIdx.x;
  if (i < NN) {
    int o = off[i] + bsum2[blockIdx.x];
    off[i] = o;
    cursor[i] = o;
  }
  if (i == 0) off[NN] = NE;
}

__global__ __launch_bounds__(256) void k_scatter(const int* __restrict__ ei,
                                                 const float* __restrict__ ew,
                                                 int* __restrict__ cursor,
                                                 int2* __restrict__ selist) {
  int e = blockIdx.x * 256 + threadIdx.x;  // grid exact 3125
  int dst = ei[NE + e];
  int pos = atomicAdd(&cursor[dst], 1);
  selist[pos] = make_int2(ei[e], __float_as_int(ew[e]));
}

// ---------------------------------------------------------------- B-panel prefetch (512-thread blocks)
// Panel = nj rows x kw halfs (kw = PC*8), staged into Bsh stride-72 (64 data +
// 8 pad halfs; 9x16B units, odd -> uniform 8-phase bank pattern for b128 reads).
// Split into load-to-reg (issue early, overlaps compute) and store-to-LDS.
template <int PC>
__device__ __forceinline__ void pf_load(half8 pf[3], const _Float16* __restrict__ W,
                                        int SR, int k0, int chunks, int t) {
#pragma unroll
  for (int u = 0; u < 3; ++u) {
    int c = t + u * 512;
    if (c < chunks) {
      int j = c / PC, p = c - j * PC;
      pf[u] = *(const half8*)&W[(size_t)j * SR + k0 + p * 8];
    }
  }
}

template <int PC>
__device__ __forceinline__ void pf_store(const half8 pf[3], _Float16* Bsh,
                                         int chunks, int t) {
#pragma unroll
  for (int u = 0; u < 3; ++u) {
    int c = t + u * 512;
    if (c < chunks) {
      int j = c / PC, p = c - j * PC;
      *(half8*)&Bsh[j * 72 + p * 8] = pf[u];
    }
  }
}

// ---------------------------------------------------------------- shared phase 2: P = tile @ Wp^T
// Precondition: Bsh holds Wp half0 slice0 (k 0..63); tile holds A (128x160, stride 168).
__device__ __forceinline__ void phase2_proj(
    const _Float16* __restrict__ Wp, const float* __restrict__ bm,
    _Float16* __restrict__ P, const _Float16* tile, _Float16* Bsh,
    int t, int w, int mrow, int quad, int n0) {
  half8 pf[3];
#pragma unroll 1
  for (int half_ = 0; half_ < 2; ++half_) {
    const _Float16* Wh = Wp + (size_t)half_ * 25600;
    floatx4 acc2[10];
#pragma unroll
    for (int i = 0; i < 10; ++i) acc2[i] = (floatx4)0.f;
    // slice 0 (k 0..63): prefetch slice 1 while computing
    pf_load<8>(pf, Wh, 160, 64, 1280, t);
#pragma unroll
    for (int h2 = 0; h2 < 2; ++h2) {
      half8 a = *(const half8*)&tile[(w * 16 + mrow) * 168 + h2 * 32 + quad * 8];
#pragma unroll
      for (int i = 0; i < 10; ++i) {
        half8 b = *(const half8*)&Bsh[(i * 16 + mrow) * 72 + h2 * 32 + quad * 8];
        acc2[i] = __builtin_amdgcn_mfma_f32_16x16x32_f16(a, b, acc2[i], 0, 0, 0);
      }
    }
    __syncthreads();
    pf_store<8>(pf, Bsh, 1280, t);
    __syncthreads();
    // slice 1 (k 64..127): prefetch slice 2 (kw=32)
    pf_load<4>(pf, Wh, 160, 128, 640, t);
#pragma unroll
    for (int h2 = 0; h2 < 2; ++h2) {
      half8 a = *(const half8*)&tile[(w * 16 + mrow) * 168 + 64 + h2 * 32 + quad * 8];
#pragma unroll
      for (int i = 0; i < 10; ++i) {
        half8 b = *(const half8*)&Bsh[(i * 16 + mrow) * 72 + h2 * 32 + quad * 8];
        acc2[i] = __builtin_amdgcn_mfma_f32_16x16x32_f16(a, b, acc2[i], 0, 0, 0);
      }
    }
    __syncthreads();
    pf_store<4>(pf, Bsh, 640, t);
    __syncthreads();
    // slice 2 (k 128..159): prefetch next half's slice 0
    if (half_ == 0) pf_load<8>(pf, Wp + 25600, 160, 0, 1280, t);
    {
      half8 a = *(const half8*)&tile[(w * 16 + mrow) * 168 + 128 + quad * 8];
#pragma unroll
      for (int i = 0; i < 10; ++i) {
        half8 b = *(const half8*)&Bsh[(i * 16 + mrow) * 72 + quad * 8];
        acc2[i] = __builtin_amdgcn_mfma_f32_16x16x32_f16(a, b, acc2[i], 0, 0, 0);
      }
    }
    // P store for this half (overlaps next-half load latency)
#pragma unroll
    for (int r = 0; r < 4; ++r) {
      const int row = quad * 4 + r;
      const int node = n0 + w * 16 + row;
      if (node < NN) {
        _Float16* prow = &P[(size_t)node * 320 + half_ * 160];
#pragma unroll
        for (int i = 0; i < 10; ++i) {
          int jj = i * 16 + mrow;
          prow[jj] = (_Float16)(acc2[i][r] + (half_ ? bm[jj] : 0.f));
        }
      }
    }
    if (half_ == 0) {
      __syncthreads();
      pf_store<8>(pf, Bsh, 1280, t);
      __syncthreads();
    }
  }
}

// ---------------------------------------------------------------- fused encoder + proj (512 thr, 128 nodes)
__global__ __launch_bounds__(512, 4) void k_encode_proj(
    const float* __restrict__ x, const float* __restrict__ tsp,
    const _Float16* __restrict__ We,
    const float* __restrict__ b_enc, const float* __restrict__ g_enc,
    const float* __restrict__ be_enc,
    const float* __restrict__ w_time, const float* __restrict__ b_time,
    const float* __restrict__ g_time, const float* __restrict__ be_time,
    const _Float16* __restrict__ Wp, const float* __restrict__ bm,
    _Float16* __restrict__ h16, _Float16* __restrict__ P) {
  __shared__ _Float16 tile[128 * 168];
  __shared__ _Float16 Bsh[160 * 72];
  const int t = threadIdx.x;
  const int lane = t & 63, w = t >> 6;
  const int mrow = lane & 15, quad = lane >> 4;
  const int n0 = blockIdx.x * 128;  // grid 782
  int arow = n0 + w * 16 + mrow; if (arow > NN - 1) arow = NN - 1;
  half8 pf[3];
  // issue slice-0 loads first
  pf_load<8>(pf, We, 128, 0, 1024, t);
  const float* xrow = x + (size_t)arow * 128;
  // A fragments (f32 -> f16) — overlaps slice-0 load latency
  half8 areg[4];
#pragma unroll
  for (int kt = 0; kt < 4; ++kt) {
    const int k0 = kt * 32 + quad * 8;
    float4 f0 = *(const float4*)&xrow[k0];
    float4 f1 = *(const float4*)&xrow[k0 + 4];
    half8 a = {(_Float16)f0.x, (_Float16)f0.y, (_Float16)f0.z, (_Float16)f0.w,
               (_Float16)f1.x, (_Float16)f1.y, (_Float16)f1.z, (_Float16)f1.w};
    areg[kt] = a;
  }
  // time-LN closed-form constants — also overlaps
  float mw = 0.f, mb = 0.f;
  for (int d = 0; d < 32; ++d) { mw += w_time[d]; mb += b_time[d]; }
  mw *= (1.f / 32.f); mb *= (1.f / 32.f);
  float A = 0.f, B = 0.f, C = 0.f;
  for (int d = 0; d < 32; ++d) {
    float a = w_time[d] - mw, c = b_time[d] - mb;
    A = fmaf(a, a, A); B = fmaf(a, c, B); C = fmaf(c, c, C);
  }
  A *= (1.f / 32.f); B *= (1.f / 32.f); C *= (1.f / 32.f);
  floatx4 acc[8];
#pragma unroll
  for (int i = 0; i < 8; ++i) acc[i] = (floatx4)0.f;
  pf_store<8>(pf, Bsh, 1024, t);
  __syncthreads();
  // slice 0 (k 0..63): prefetch slice 1
  pf_load<8>(pf, We, 128, 64, 1024, t);
#pragma unroll
  for (int h2 = 0; h2 < 2; ++h2) {
    half8 a = areg[h2];
#pragma unroll
    for (int i = 0; i < 8; ++i) {
      half8 b = *(const half8*)&Bsh[(i * 16 + mrow) * 72 + h2 * 32 + quad * 8];
      acc[i] = __builtin_amdgcn_mfma_f32_16x16x32_f16(a, b, acc[i], 0, 0, 0);
    }
  }
  __syncthreads();
  pf_store<8>(pf, Bsh, 1024, t);
  __syncthreads();
  // slice 1 (k 64..127): prefetch phase-2 Wp half0 slice0
  pf_load<8>(pf, Wp, 160, 0, 1280, t);
#pragma unroll
  for (int h2 = 0; h2 < 2; ++h2) {
    half8 a = areg[2 + h2];
#pragma unroll
    for (int i = 0; i < 8; ++i) {
      half8 b = *(const half8*)&Bsh[(i * 16 + mrow) * 72 + h2 * 32 + quad * 8];
      acc[i] = __builtin_amdgcn_mfma_f32_16x16x32_f16(a, b, acc[i], 0, 0, 0);
    }
  }
  // epilogue: LN(128) + relu -> tile + h16
#pragma unroll
  for (int r = 0; r < 4; ++r) {
    const int row = quad * 4 + r;
    const int node = n0 + w * 16 + row;
    float v[8], s = 0.f, ss = 0.f;
#pragma unroll
    for (int i = 0; i < 8; ++i) {
      v[i] = acc[i][r] + b_enc[i * 16 + mrow];
      s += v[i]; ss = fmaf(v[i], v[i], ss);
    }
#pragma unroll
    for (int off = 1; off < 16; off <<= 1) { s += __shfl_xor(s, off); ss += __shfl_xor(ss, off); }
    const float m = s * (1.f / 128.f);
    const float rs = rsqrtf(ss * (1.f / 128.f) - m * m + 1e-5f);
#pragma unroll
    for (int i = 0; i < 8; ++i) {
      int j = i * 16 + mrow;
      float y = fmaxf(fmaf((v[i] - m) * rs, g_enc[j], be_enc[j]), 0.f);
      tile[(w * 16 + row) * 168 + j] = (_Float16)y;
      if (node < NN) h16[(size_t)node * 160 + j] = (_Float16)y;
    }
  }
  // time dims 128..159 (closed-form LN): 128 nodes x 32 dims = 4096
#pragma unroll
  for (int r2 = 0; r2 < 8; ++r2) {
    int q = t + r2 * 512;
    int nn = q >> 5, d = q & 31;
    int node = n0 + nn;
    int nodec = (node > NN - 1) ? NN - 1 : node;
    float tsv = tsp[nodec];
    float mt = fmaf(mw, tsv, mb);
    float rst = rsqrtf(fmaf(fmaf(A, tsv, 2.f * B), tsv, C) + 1e-5f);
    float vv = fmaf(w_time[d], tsv, b_time[d]);
    float y = fmaxf(fmaf((vv - mt) * rst, g_time[d], be_time[d]), 0.f);
    tile[nn * 168 + 128 + d] = (_Float16)y;
    if (node < NN) h16[(size_t)node * 160 + 128 + d] = (_Float16)y;
  }
  __syncthreads();
  pf_store<8>(pf, Bsh, 1280, t);
  __syncthreads();
  phase2_proj(Wp, bm, P, tile, Bsh, t, w, mrow, quad, n0);
}

// ---------------------------------------------------------------- edge aggregate (CSR, 2-way unroll)
__global__ __launch_bounds__(256) void k_edge3(
    const _Float16* __restrict__ P, const int* __restrict__ off,
    const int2* __restrict__ selist,
    const float* __restrict__ gm, const float* __restrict__ bem,
    _Float16* __restrict__ msum16) {
  const int t = threadIdx.x;
  const int jg = t & 31, g = t >> 5;
  const int n = blockIdx.x * 8 + g;  // grid exact: 12500*8 = 100000
  float gmv[5], bev[5], pdv[5];
#pragma unroll
  for (int i = 0; i < 4; ++i) { gmv[i] = gm[4 * jg + i]; bev[i] = bem[4 * jg + i]; }
  gmv[4] = gm[128 + jg]; bev[4] = bem[128 + jg];
  const _Float16* pd = P + (size_t)n * 320 + 160;
  half4 pdh = *(const half4*)&pd[4 * jg];
  pdv[0] = (float)pdh.x; pdv[1] = (float)pdh.y; pdv[2] = (float)pdh.z; pdv[3] = (float)pdh.w;
  pdv[4] = (float)pd[128 + jg];
  float acc[5] = {0.f, 0.f, 0.f, 0.f, 0.f};
  const int e0 = off[n], e1 = off[n + 1];
  int k = e0;
  for (; k + 1 < e1; k += 2) {
    int2 seA = selist[k], seB = selist[k + 1];
    const _Float16* psA = P + (size_t)seA.x * 320;
    const _Float16* psB = P + (size_t)seB.x * 320;
    const float weA = __int_as_float(seA.y), weB = __int_as_float(seB.y);
    half4 a4 = *(const half4*)&psA[4 * jg];
    half4 b4 = *(const half4*)&psB[4 * jg];
    float a5 = (float)psA[128 + jg], b5 = (float)psB[128 + jg];
    float vA[5], vB[5];
    vA[0] = (float)a4.x + pdv[0]; vA[1] = (float)a4.y + pdv[1];
    vA[2] = (float)a4.z + pdv[2]; vA[3] = (float)a4.w + pdv[3]; vA[4] = a5 + pdv[4];
    vB[0] = (float)b4.x + pdv[0]; vB[1] = (float)b4.y + pdv[1];
    vB[2] = (float)b4.z + pdv[2]; vB[3] = (float)b4.w + pdv[3]; vB[4] = b5 + pdv[4];
    float sA = 0.f, ssA = 0.f, sB = 0.f, ssB = 0.f;
#pragma unroll
    for (int i = 0; i < 5; ++i) {
      sA += vA[i]; ssA = fmaf(vA[i], vA[i], ssA);
      sB += vB[i]; ssB = fmaf(vB[i], vB[i], ssB);
    }
#pragma unroll
    for (int o = 1; o < 32; o <<= 1) {
      sA += __shfl_xor(sA, o); ssA += __shfl_xor(ssA, o);
      sB += __shfl_xor(sB, o); ssB += __shfl_xor(ssB, o);
    }
    const float mA = sA * (1.f / 160.f), mB = sB * (1.f / 160.f);
    const float rsA = rsqrtf(ssA * (1.f / 160.f) - mA * mA + 1e-5f);
    const float rsB = rsqrtf(ssB * (1.f / 160.f) - mB * mB + 1e-5f);
#pragma unroll
    for (int i = 0; i < 5; ++i) {
      acc[i] = fmaf(fmaxf(fmaf((vA[i] - mA) * rsA, gmv[i], bev[i]), 0.f), weA, acc[i]);
      acc[i] = fmaf(fmaxf(fmaf((vB[i] - mB) * rsB, gmv[i], bev[i]), 0.f), weB, acc[i]);
    }
  }
  if (k < e1) {
    int2 se = selist[k];
    const _Float16* ps = P + (size_t)se.x * 320;
    const float we = __int_as_float(se.y);
    half4 s4 = *(const half4*)&ps[4 * jg];
    float v[5], s = 0.f, ss = 0.f;
    v[0] = (float)s4.x + pdv[0]; v[1] = (float)s4.y + pdv[1];
    v[2] = (float)s4.z + pdv[2]; v[3] = (float)s4.w + pdv[3];
    v[4] = (float)ps[128 + jg] + pdv[4];
#pragma unroll
    for (int i = 0; i < 5; ++i) { s += v[i]; ss = fmaf(v[i], v[i], ss); }
#pragma unroll
    for (int o = 1; o < 32; o <<= 1) { s += __shfl_xor(s, o); ss += __shfl_xor(ss, o); }
    const float m = s * (1.f / 160.f);
    const float rs = rsqrtf(ss * (1.f / 160.f) - m * m + 1e-5f);
#pragma unroll
    for (int i = 0; i < 5; ++i)
      acc[i] = fmaf(fmaxf(fmaf((v[i] - m) * rs, gmv[i], bev[i]), 0.f), we, acc[i]);
  }
  const float c = (float)(e1 - e0);
  const float ic = (c > 0.f) ? 1.f / (c + 1e-8f) : 0.f;
  _Float16* orow = msum16 + (size_t)n * 160;
  half4 o4 = {(_Float16)(acc[0] * ic), (_Float16)(acc[1] * ic),
              (_Float16)(acc[2] * ic), (_Float16)(acc[3] * ic)};
  *(half4*)&orow[4 * jg] = o4;
  orow[128 + jg] = (_Float16)(acc[4] * ic);
}

// ---------------------------------------------------------------- fused update + proj (512 thr, 128 nodes)
__global__ __launch_bounds__(512, 4) void k_update_proj(
    _Float16* __restrict__ h16, const _Float16* __restrict__ msum16,
    const _Float16* __restrict__ Wu, const float* __restrict__ bu,
    const float* __restrict__ gu, const float* __restrict__ beu,
    const float* __restrict__ wg, const float* __restrict__ bg,
    const _Float16* __restrict__ Wp, const float* __restrict__ bm,
    _Float16* __restrict__ P) {
  __shared__ _Float16 tile[128 * 168];
  __shared__ _Float16 Bsh[160 * 72];
  const int t = threadIdx.x;
  const int lane = t & 63, w = t >> 6;
  const int mrow = lane & 15, quad = lane >> 4;
  const int n0 = blockIdx.x * 128;  // grid 782
  int arow = n0 + w * 16 + mrow; if (arow > NN - 1) arow = NN - 1;
  half8 pf[3];
  pf_load<8>(pf, Wu, 320, 0, 1280, t);  // slice 0, issued first
  const _Float16* hrowp = h16 + (size_t)arow * 160;
  const _Float16* mrowp = msum16 + (size_t)arow * 160;
  // A fragments — overlap slice-0 load latency
  half8 areg[10];
#pragma unroll
  for (int kt = 0; kt < 5; ++kt) areg[kt] = *(const half8*)&hrowp[kt * 32 + quad * 8];
#pragma unroll
  for (int kt = 5; kt < 10; ++kt) areg[kt] = *(const half8*)&mrowp[kt * 32 + quad * 8 - 160];
  // gate dot from hoisted h-fragments
  float gp = 0.f;
#pragma unroll
  for (int kt = 0; kt < 5; ++kt) {
    const int k0 = kt * 32 + quad * 8;
    float4 g0 = *(const float4*)&wg[k0];
    float4 g1 = *(const float4*)&wg[k0 + 4];
    gp = fmaf((float)areg[kt][0], g0.x, gp); gp = fmaf((float)areg[kt][1], g0.y, gp);
    gp = fmaf((float)areg[kt][2], g0.z, gp); gp = fmaf((float)areg[kt][3], g0.w, gp);
    gp = fmaf((float)areg[kt][4], g1.x, gp); gp = fmaf((float)areg[kt][5], g1.y, gp);
    gp = fmaf((float)areg[kt][6], g1.z, gp); gp = fmaf((float)areg[kt][7], g1.w, gp);
  }
  gp += __shfl_xor(gp, 16); gp += __shfl_xor(gp, 32);
  const float twv = 1.f / (1.f + expf(-(gp + bg[0])));
  floatx4 acc[10];
#pragma unroll
  for (int i = 0; i < 10; ++i) acc[i] = (floatx4)0.f;
  pf_store<8>(pf, Bsh, 1280, t);
  __syncthreads();
#pragma unroll
  for (int ks = 0; ks < 5; ++ks) {
    // prefetch next panel while computing this one
    if (ks < 4) pf_load<8>(pf, Wu, 320, (ks + 1) * 64, 1280, t);
    else        pf_load<8>(pf, Wp, 160, 0, 1280, t);  // phase-2 half0 slice0
#pragma unroll
    for (int h2 = 0; h2 < 2; ++h2) {
      half8 a = areg[ks * 2 + h2];
#pragma unroll
      for (int i = 0; i < 10; ++i) {
        half8 b = *(const half8*)&Bsh[(i * 16 + mrow) * 72 + h2 * 32 + quad * 8];
        acc[i] = __builtin_amdgcn_mfma_f32_16x16x32_f16(a, b, acc[i], 0, 0, 0);
      }
    }
    if (ks == 4) {
      // epilogue: LN + relu + gate blend -> tile + h16
#pragma unroll
      for (int r = 0; r < 4; ++r) {
        const int row = quad * 4 + r;
        const int node = n0 + w * 16 + row;
        const int nodec = (node > NN - 1) ? NN - 1 : node;
        float v[10], s = 0.f, ss = 0.f;
#pragma unroll
        for (int i = 0; i < 10; ++i) {
          v[i] = acc[i][r] + bu[i * 16 + mrow];
          s += v[i]; ss = fmaf(v[i], v[i], ss);
        }
#pragma unroll
        for (int off = 1; off < 16; off <<= 1) { s += __shfl_xor(s, off); ss += __shfl_xor(ss, off); }
        const float m = s * (1.f / 160.f);
        const float rs = rsqrtf(ss * (1.f / 160.f) - m * m + 1e-5f);
        const float g = __shfl(twv, row);
        const _Float16* hr = h16 + (size_t)nodec * 160;
#pragma unroll
        for (int i = 0; i < 10; ++i) {
          int j = i * 16 + mrow;
          float hnew = fmaxf(fmaf((v[i] - m) * rs, gu[j], beu[j]), 0.f);
          float hold = (float)hr[j];
          float hupd = fmaf(g, hnew - hold, hold);
          tile[(w * 16 + row) * 168 + j] = (_Float16)hupd;
          if (node < NN) h16[(size_t)node * 160 + j] = (_Float16)hupd;
        }
      }
    }
    __syncthreads();
    pf_store<8>(pf, Bsh, 1280, t);
    __syncthreads();
  }
  phase2_proj(Wp, bm, P, tile, Bsh, t, w, mrow, quad, n0);
}

// ---------------------------------------------------------------- fused update + output proj + L2 norm
__global__ __launch_bounds__(512, 4) void k_update_out(
    const _Float16* __restrict__ h16, const _Float16* __restrict__ msum16,
    const _Float16* __restrict__ Wu, const float* __restrict__ bu,
    const float* __restrict__ gu, const float* __restrict__ beu,
    const float* __restrict__ wg, const float* __restrict__ bg,
    const _Float16* __restrict__ Wo, const float* __restrict__ b_out,
    float* __restrict__ out) {
  __shared__ _Float16 tile[128 * 168];
  __shared__ _Float16 Bsh[160 * 72];
  const int t = threadIdx.x;
  const int lane = t & 63, w = t >> 6;
  const int mrow = lane & 15, quad = lane >> 4;
  const int n0 = blockIdx.x * 128;  // grid 782
  int arow = n0 + w * 16 + mrow; if (arow > NN - 1) arow = NN - 1;
  half8 pf[3];
  pf_load<8>(pf, Wu, 320, 0, 1280, t);
  const _Float16* hrowp = h16 + (size_t)arow * 160;
  const _Float16* mrowp = msum16 + (size_t)arow * 160;
  half8 areg[10];
#pragma unroll
  for (int kt = 0; kt < 5; ++kt) areg[kt] = *(const half8*)&hrowp[kt * 32 + quad * 8];
#pragma unroll
  for (int kt = 5; kt < 10; ++kt) areg[kt] = *(const half8*)&mrowp[kt * 32 + quad * 8 - 160];
  float gp = 0.f;
#pragma unroll
  for (int kt = 0; kt < 5; ++kt) {
    const int k0 = kt * 32 + quad * 8;
    float4 g0 = *(const float4*)&wg[k0];
    float4 g1 = *(const float4*)&wg[k0 + 4];
    gp = fmaf((float)areg[kt][0], g0.x, gp); gp = fmaf((float)areg[kt][1], g0.y, gp);
    gp = fmaf((float)areg[kt][2], g0.z, gp); gp = fmaf((float)areg[kt][3], g0.w, gp);
    gp = fmaf((float)areg[kt][4], g1.x, gp); gp = fmaf((float)areg[kt][5], g1.y, gp);
    gp = fmaf((float)areg[kt][6], g1.z, gp); gp = fmaf((float)areg[kt][7], g1.w, gp);
  }
  gp += __shfl_xor(gp, 16); gp += __shfl_xor(gp, 32);
  const float twv = 1.f / (1.f + expf(-(gp + bg[0])));
  floatx4 acc[10];
#pragma unroll
  for (int i = 0; i < 10; ++i) acc[i] = (floatx4)0.f;
  pf_store<8>(pf, Bsh, 1280, t);
  __syncthreads();
#pragma unroll
  for (int ks = 0; ks < 5; ++ks) {
    if (ks < 4) pf_load<8>(pf, Wu, 320, (ks + 1) * 64, 1280, t);
    else        pf_load<8>(pf, Wo, 160, 0, 1024, t);  // phase-2 slice 0 (128 rows)
#pragma unroll
    for (int h2 = 0; h2 < 2; ++h2) {
      half8 a = areg[ks * 2 + h2];
#pragma unroll
      for (int i = 0; i < 10; ++i) {
        half8 b = *(const half8*)&Bsh[(i * 16 + mrow) * 72 + h2 * 32 + quad * 8];
        acc[i] = __builtin_amdgcn_mfma_f32_16x16x32_f16(a, b, acc[i], 0, 0, 0);
      }
    }
    if (ks == 4) {
#pragma unroll
      for (int r = 0; r < 4; ++r) {
        const int row = quad * 4 + r;
        const int node = n0 + w * 16 + row;
        const int nodec = (node > NN - 1) ? NN - 1 : node;
        float v[10], s = 0.f, ss = 0.f;
#pragma unroll
        for (int i = 0; i < 10; ++i) {
          v[i] = acc[i][r] + bu[i * 16 + mrow];
          s += v[i]; ss = fmaf(v[i], v[i], ss);
        }
#pragma unroll
        for (int off = 1; off < 16; off <<= 1) { s += __shfl_xor(s, off); ss += __shfl_xor(ss, off); }
        const float m = s * (1.f / 160.f);
        const float rs = rsqrtf(ss * (1.f / 160.f) - m * m + 1e-5f);
        const float g = __shfl(twv, row);
        const _Float16* hr = h16 + (size_t)nodec * 160;
#pragma unroll
        for (int i = 0; i < 10; ++i) {
          int j = i * 16 + mrow;
          float hnew = fmaxf(fmaf((v[i] - m) * rs, gu[j], beu[j]), 0.f);
          float hold = (float)hr[j];
          tile[(w * 16 + row) * 168 + j] = (_Float16)fmaf(g, hnew - hold, hold);  // final h: LDS only
        }
      }
    }
    __syncthreads();
    pf_store<8>(pf, Bsh, (ks < 4) ? 1280 : 1024, t);
    __syncthreads();
  }
  // ---- phase 2: out = L2norm(tile @ Wo^T + b_out); 128 cols, K=160
  floatx4 acc2[8];
#pragma unroll
  for (int i = 0; i < 8; ++i) acc2[i] = (floatx4)0.f;
  // slice 0 (k 0..63): prefetch slice 1
  pf_load<8>(pf, Wo, 160, 64, 1024, t);
#pragma unroll
  for (int h2 = 0; h2 < 2; ++h2) {
    half8 a = *(const half8*)&tile[(w * 16 + mrow) * 168 + h2 * 32 + quad * 8];
#pragma unroll
    for (int i = 0; i < 8; ++i) {
      half8 b = *(const half8*)&Bsh[(i * 16 + mrow) * 72 + h2 * 32 + quad * 8];
      acc2[i] = __builtin_amdgcn_mfma_f32_16x16x32_f16(a, b, acc2[i], 0, 0, 0);
    }
  }
  __syncthreads();
  pf_store<8>(pf, Bsh, 1024, t);
  __syncthreads();
  // slice 1 (k 64..127): prefetch slice 2 (kw=32)
  pf_load<4>(pf, Wo, 160, 128, 512, t);
#pragma unroll
  for (int h2 = 0; h2 < 2; ++h2) {
    half8 a = *(const half8*)&tile[(w * 16 + mrow) * 168 + 64 + h2 * 32 + quad * 8];
#pragma unroll
    for (int i = 0; i < 8; ++i) {
      half8 b = *(const half8*)&Bsh[(i * 16 + mrow) * 72 + h2 * 32 + quad * 8];
      acc2[i] = __builtin_amdgcn_mfma_f32_16x16x32_f16(a, b, acc2[i], 0, 0, 0);
    }
  }
  __syncthreads();
  pf_store<4>(pf, Bsh, 512, t);
  __syncthreads();
  // slice 2 (k 128..159)
  {
    half8 a = *(const half8*)&tile[(w * 16 + mrow) * 168 + 128 + quad * 8];
#pragma unroll
    for (int i = 0; i < 8; ++i) {
      half8 b = *(const half8*)&Bsh[(i * 16 + mrow) * 72 + quad * 8];
      acc2[i] = __builtin_amdgcn_mfma_f32_16x16x32_f16(a, b, acc2[i], 0, 0, 0);
    }
  }
#pragma unroll
  for (int r = 0; r < 4; ++r) {
    const int row = quad * 4 + r;
    const int node = n0 + w * 16 + row;
    float v[8], ss = 0.f;
#pragma unroll
    for (int i = 0; i < 8; ++i) {
      v[i] = acc2[i][r] + b_out[i * 16 + mrow];
      ss = fmaf(v[i], v[i], ss);
    }
#pragma unroll
    for (int off = 1; off < 16; off <<= 1) ss += __shfl_xor(ss, off);
    const float inv = 1.f / fmaxf(sqrtf(ss), 1e-12f);
    if (node < NN) {
#pragma unroll
      for (int i = 0; i < 8; ++i)
        out[(size_t)node * 128 + i * 16 + mrow] = v[i] * inv;
    }
  }
}

// ---------------------------------------------------------------- launch
extern "C" void kernel_launch(void* const* d_in, const int* in_sizes, int n_in,
                              void* d_out, int out_size, void* d_ws, size_t ws_size,
                              hipStream_t stream) {
  (void)in_sizes; (void)n_in; (void)out_size; (void)ws_size;
  const float* x       = (const float*)d_in[0];
  const int*   ei      = (const int*)  d_in[1];
  const float* ew      = (const float*)d_in[2];
  const float* tsp     = (const float*)d_in[3];
  const float* w_enc   = (const float*)d_in[4];
  const float* b_enc   = (const float*)d_in[5];
  const float* g_enc   = (const float*)d_in[6];
  const float* be_enc  = (const float*)d_in[7];
  const float* w_time  = (const float*)d_in[8];
  const float* b_time  = (const float*)d_in[9];
  const float* g_time  = (const float*)d_in[10];
  const float* be_time = (const float*)d_in[11];
  const float* wm      = (const float*)d_in[12];
  const float* bm      = (const float*)d_in[13];
  const float* gm      = (const float*)d_in[14];
  const float* bem     = (const float*)d_in[15];
  const float* wu      = (const float*)d_in[16];
  const float* bu      = (const float*)d_in[17];
  const float* gu      = (const float*)d_in[18];
  const float* beu     = (const float*)d_in[19];
  const float* wg      = (const float*)d_in[20];
  const float* bg      = (const float*)d_in[21];
  const float* w_out   = (const float*)d_in[22];
  const float* b_out   = (const float*)d_in[23];
  float* out = (float*)d_out;

  // ws layout (bytes): h16 f16[NN*160] @0 (32M) | msum16 f16[NN*160] @32,000,000 (32M)
  //   P f16[NN*320] @64,000,000 (64M) | Wu16 @128,000,000 (204,800) | Wo16 @128,204,800 (40,960)
  char* ws = (char*)d_ws;
  _Float16* h16     = (_Float16*)ws;
  _Float16* msum16  = (_Float16*)(ws + 32000000);
  _Float16* P       = (_Float16*)(ws + 64000000);
  _Float16* Wu16    = (_Float16*)(ws + 128000000);
  _Float16* Wo16    = (_Float16*)(ws + 128204800);
  // d_out doubles as scratch; k_update_out reads only ws-resident scratch.
  char* ob = (char*)d_out;
  _Float16* Wp16 = (_Float16*)ob;             // 204,800
  _Float16* We16 = (_Float16*)(ob + 204800);  // 32,768
  int* off    = (int*)(ob + 237568);          // 400,016
  int* cnti   = (int*)(ob + 637584);          // 400,000
  int* cursor = (int*)(ob + 1037584);         // 400,000
  int* bsum   = (int*)(ob + 1437584);         // 1,568
  int* bsum2  = (int*)(ob + 1439152);         // 1,568
  int2* selist = (int2*)(ob + 1440720);       // 6,400,000 -> 7,840,720 < 51,200,000

  // weight prep + CSR build (edges static across layers: build once)
  k_zero<<<dim3(98), dim3(256), 0, stream>>>((float4*)cnti, 25000);
  k_cast<<<dim3(400), dim3(256), 0, stream>>>(wu, Wu16, 102400);
  k_cast<<<dim3(64),  dim3(256), 0, stream>>>(w_enc, We16, 16384);
  k_cast<<<dim3(80),  dim3(256), 0, stream>>>(w_out, Wo16, 20480);
  k_prep_wm<<<dim3(400), dim3(256), 0, stream>>>(wm, Wp16);
  k_count_i<<<dim3(3125), dim3(256), 0, stream>>>(ei, cnti);
  k_scan1<<<dim3(391), dim3(256), 0, stream>>>(cnti, off, bsum);
  k_scan2<<<dim3(1), dim3(512), 0, stream>>>(bsum, bsum2);
  k_scan3<<<dim3(391), dim3(256), 0, stream>>>(off, bsum2, cursor);
  k_scatter<<<dim3(3125), dim3(256), 0, stream>>>(ei, ew, cursor, selist);

  k_encode_proj<<<dim3(782), dim3(512), 0, stream>>>(
      x, tsp, We16, b_enc, g_enc, be_enc, w_time, b_time, g_time, be_time,
      Wp16, bm, h16, P);
  k_edge3<<<dim3(12500), dim3(256), 0, stream>>>(P, off, selist, gm, bem, msum16);
  k_update_proj<<<dim3(782), dim3(512), 0, stream>>>(
      h16, msum16, Wu16, bu, gu, beu, wg, bg,
      Wp16 + 51200, bm + 160, P);
  k_edge3<<<dim3(12500), dim3(256), 0, stream>>>(P, off, selist, gm + 160, bem + 160, msum16);
  k_update_out<<<dim3(782), dim3(512), 0, stream>>>(
      h16, msum16, Wu16 + 51200, bu + 160, gu + 160, beu + 160, wg + 160, bg + 1,
      Wo16, b_out, out);
}